// Round 21
// baseline (36.889 us; speedup 1.0000x reference)
//
#include <hip/hip_runtime.h>

#define B 16
#define C 64
#define SS 4096      // H*W
#define TT 1024      // pooled keys
#define CQ 8         // C/8
#define CG 32        // C/2

typedef _Float16 h4 __attribute__((ext_vector_type(4)));
typedef float f32x16 __attribute__((ext_vector_type(16)));

#if __has_builtin(__builtin_amdgcn_exp2f)
#define EXP2(x) __builtin_amdgcn_exp2f(x)
#else
#define EXP2(x) exp2f(x)
#endif

#define MFMA328(a, b, c) __builtin_amdgcn_mfma_f32_32x32x8f16((a), (b), (c), 0, 0, 0)

// ---------------------------------------------------------------------------
// KP: projections via MFMA, zero LDS, zero barriers (R11-proven version).
// Outputs: theta_t[b][s][o] f16 (o-contig, pre-scaled log2e), phi_t[b][t][o],
//          g_blk[b][t>>2][c][t&3] f16 (blocked: contiguous per batch)
// ---------------------------------------------------------------------------
__global__ __launch_bounds__(256) void k_proj(
        const float* __restrict__ x, const float* __restrict__ w_theta,
        const float* __restrict__ w_phi, const float* __restrict__ w_g,
        _Float16* __restrict__ theta_t, _Float16* __restrict__ phi_t,
        _Float16* __restrict__ g_blk) {
    int tid = threadIdx.x;
    int W = blockIdx.x * 4 + (tid >> 6);     // 1024 wave-tasks
    int l = tid & 63;
    int ln = l & 31, hi = l >> 5;
    int b = W >> 6, ws = W & 63;
    int rp = ws >> 1, wt = ws & 1;           // row-pair 0..31, w-tile 0..1
    int sA = rp * 128 + wt * 32 + ln;        // pixel (2rp, 32wt+ln)

    // ---- A-fragments (weights), loaded once ----
    const float LOG2E = 1.44269504088896f;
    float wsc = 1.f;
    const float* wr0;
    if (ln < 8)       { wr0 = w_theta + ln * C; wsc = LOG2E; }
    else if (ln < 16) { wr0 = w_phi + (ln - 8) * C; }
    else              { wr0 = w_g + (ln - 16) * C; }
    const float* wr1 = w_g + (16 + (ln & 15)) * C;  // used only when ln<16
    bool t1v = ln < 16;

    h4 wa0[8], wa1[8];
#pragma unroll
    for (int kk = 0; kk < 8; ++kk) {
        float4 v0 = *(const float4*)&wr0[8 * kk + 4 * hi];
        float4 v1 = *(const float4*)&wr1[8 * kk + 4 * hi];
        wa0[kk][0] = (_Float16)(v0.x * wsc);
        wa0[kk][1] = (_Float16)(v0.y * wsc);
        wa0[kk][2] = (_Float16)(v0.z * wsc);
        wa0[kk][3] = (_Float16)(v0.w * wsc);
        wa1[kk][0] = t1v ? (_Float16)v1.x : (_Float16)0.f;
        wa1[kk][1] = t1v ? (_Float16)v1.y : (_Float16)0.f;
        wa1[kk][2] = t1v ? (_Float16)v1.z : (_Float16)0.f;
        wa1[kk][3] = t1v ? (_Float16)v1.w : (_Float16)0.f;
    }

    // ---- x loads: 64 independent coalesced scalar f32 per lane ----
    const float* xb = x + ((size_t)b << 18);
    float xA[8][4], xB[8][4];
#pragma unroll
    for (int kk = 0; kk < 8; ++kk)
#pragma unroll
        for (int i = 0; i < 4; ++i) {
            int c = 8 * kk + 4 * hi + i;
            xA[kk][i] = xb[((size_t)c << 12) + sA];
            xB[kk][i] = xb[((size_t)c << 12) + sA + 64];
        }

    f32x16 aA0, aA1, aB0, aB1;
#pragma unroll
    for (int r = 0; r < 16; ++r) { aA0[r] = 0.f; aA1[r] = 0.f; aB0[r] = 0.f; aB1[r] = 0.f; }

#pragma unroll
    for (int kk = 0; kk < 8; ++kk) {
        h4 bA, bB;
#pragma unroll
        for (int i = 0; i < 4; ++i) {
            bA[i] = (_Float16)xA[kk][i];
            bB[i] = (_Float16)xB[kk][i];
        }
        aA0 = MFMA328(wa0[kk], bA, aA0);
        aB0 = MFMA328(wa0[kk], bB, aB0);
        aA1 = MFMA328(wa1[kk], bA, aA1);
        aB1 = MFMA328(wa1[kk], bB, aB1);
    }

    // ---- theta (rows 0-7 = regs 0-3 + 4hi), no pooling ----
    {
        h4 tv;
#pragma unroll
        for (int r = 0; r < 4; ++r) tv[r] = (_Float16)aA0[r];
        *(h4*)&theta_t[(size_t)((b << 12) + sA) * 8 + 4 * hi] = tv;
#pragma unroll
        for (int r = 0; r < 4; ++r) tv[r] = (_Float16)aB0[r];
        *(h4*)&theta_t[(size_t)((b << 12) + sA + 64) * 8 + 4 * hi] = tv;
    }

    // ---- pooled phi / g ----
    int t = rp * 32 + wt * 16 + (ln >> 1);
    float pv[4];
#pragma unroll
    for (int j = 0; j < 4; ++j) {
        float m = fmaxf(aA0[4 + j], aB0[4 + j]);
        m = fmaxf(m, __shfl_xor(m, 1));
        pv[j] = m;
    }
    float gv[4][4];
#pragma unroll
    for (int j = 0; j < 4; ++j) {
        float m0 = fmaxf(aA0[8 + j],  aB0[8 + j]);
        float m1 = fmaxf(aA0[12 + j], aB0[12 + j]);
        float m2 = fmaxf(aA1[j],      aB1[j]);
        float m3 = fmaxf(aA1[4 + j],  aB1[4 + j]);
        gv[0][j] = fmaxf(m0, __shfl_xor(m0, 1));
        gv[1][j] = fmaxf(m1, __shfl_xor(m1, 1));
        gv[2][j] = fmaxf(m2, __shfl_xor(m2, 1));
        gv[3][j] = fmaxf(m3, __shfl_xor(m3, 1));
    }
    if ((l & 1) == 0) {
        h4 pj;
#pragma unroll
        for (int j = 0; j < 4; ++j) pj[j] = (_Float16)pv[j];
        *(h4*)&phi_t[(size_t)((b << 10) + t) * 8 + 4 * hi] = pj;
        // blocked g: [b][t>>2][c][t&3]
        _Float16* gb = g_blk + ((size_t)(b * 256 + (t >> 2)) * 32) * 4 + (t & 3);
#pragma unroll
        for (int part = 0; part < 4; ++part) {
            int cbase = part * 8 + 4 * hi;
#pragma unroll
            for (int j = 0; j < 4; ++j)
                gb[(size_t)(cbase + j) * 4] = (_Float16)gv[part][j];
        }
    }
}

// ---------------------------------------------------------------------------
// KA: split-K flash attention, SINGLE-PASS online softmax on the R20 LDS
// structure. 512 blocks x 8 waves; wave pair (w, w+4) shares 32 query rows,
// each half handles 512 keys (16 chunks). g+phi staged in 80 KB LDS (linear
// coalesced copies); online max (chunk-0 peeled, rescale of both split
// accumulators only on __any growth, cneg rebuilt then); depth-1 LDS
// prefetch; max3-shaped chunk-max tree. Flash max-merge combine through
// overlaid LDS (barrier-separated); epilogue split by channel-half.
// ---------------------------------------------------------------------------
__global__ __launch_bounds__(512, 4) void k_attn(
        const float* __restrict__ x, const _Float16* __restrict__ theta_t,
        const _Float16* __restrict__ phi_t, const _Float16* __restrict__ g_blk,
        const float* __restrict__ w_o, const float* __restrict__ gamma_p,
        float* __restrict__ out) {
    __shared__ __align__(16) char smem[81920];       // g 64K | phi 16K
    _Float16* g_sh   = (_Float16*)smem;
    _Float16* phi_sh = (_Float16*)(smem + 65536);
    float (*accx)[16][64] = (float (*)[16][64])smem; // overlay (g dead)
    float (*mlx)[2][64]   = (float (*)[2][64])(smem + 32768);

    int tid = threadIdx.x;
    int bid = blockIdx.x;
    int wg = (bid & 7) * 64 + (bid >> 3);    // XCD-contiguous (512 = 8*64)
    int b = wg >> 5;
    int s0 = (wg & 31) * 128;
    int w = tid >> 6;
    int l = tid & 63;
    int ln = l & 31, hi = l >> 5;
    int sub = w & 3, half = w >> 2;
    int sw = s0 + sub * 32;
    int h16 = half * 16;                     // this half's chunk base

    // ---- stage g (64 KB) + phi (16 KB): linear coalesced copies ----
    {
        const float4* srcg = (const float4*)(g_blk + (size_t)b * (256 * 128));
        float4* dstg = (float4*)smem;
#pragma unroll
        for (int i = 0; i < 8; ++i)
            dstg[tid + 512 * i] = srcg[tid + 512 * i];
        const float4* srcp = (const float4*)(phi_t + ((size_t)b << 10) * 8);
        float4* dstp = (float4*)phi_sh;
#pragma unroll
        for (int i = 0; i < 2; ++i)
            dstp[tid + 512 * i] = srcp[tid + 512 * i];
    }

    // theta B-fragment (col s = sw+ln, k = o = 4*hi+i), loop-invariant
    h4 bth = *(const h4*)&theta_t[(size_t)((b << 12) + sw + ln) * 8 + 4 * hi];

    f32x16 zero;
#pragma unroll
    for (int r = 0; r < 16; ++r) zero[r] = 0.f;

#define LD_PHI_S(t_) (*(const h4*)&phi_sh[(size_t)((t_) * 32 + ln) * 8 + 4 * hi])
#define LD_G_S(dst, t_)                                                        \
    {                                                                          \
        _Pragma("unroll")                                                      \
        for (int kk = 0; kk < 4; ++kk)                                         \
            dst[kk] = *(const h4*)&g_sh[(size_t)(((t_) * 8 + 2 * kk + hi) * 32 + ln) * 4]; \
    }
    // max3-friendly reduction: nested triples fuse to v_max3_f32
#define FMAX16(dst, sc_)                                                       \
    {                                                                          \
        float t0 = fmaxf(fmaxf(sc_[0], sc_[1]), sc_[2]);                       \
        float t1 = fmaxf(fmaxf(sc_[3], sc_[4]), sc_[5]);                       \
        float t2 = fmaxf(fmaxf(sc_[6], sc_[7]), sc_[8]);                       \
        float t3 = fmaxf(fmaxf(sc_[9], sc_[10]), sc_[11]);                     \
        float t4 = fmaxf(fmaxf(sc_[12], sc_[13]), sc_[14]);                    \
        float u0 = fmaxf(fmaxf(t0, t1), t2);                                   \
        float u1 = fmaxf(fmaxf(t3, t4), sc_[15]);                              \
        dst = fmaxf(dst, fmaxf(u0, u1));                                       \
    }

    __syncthreads();   // staging complete

    // ---- single pass: online softmax + PV accumulate, all reads from LDS ----
    f32x16 accE = zero, accO = zero;
    float lsum = 0.f;
    float mx;
    f32x16 cneg;

    h4 ap = LD_PHI_S(h16);
    h4 ag[4];
    LD_G_S(ag, h16);

    // peel chunk 0 (sets mx, no rescale path)
    {
        int tn = h16 + 1;
        h4 apn = LD_PHI_S(tn);
        h4 agn[4];
        LD_G_S(agn, tn);

        f32x16 sc = MFMA328(ap, bth, zero);
        float cm = -1e30f;
        FMAX16(cm, sc);
        cm = fmaxf(cm, __shfl_xor(cm, 32));
        mx = cm;
#pragma unroll
        for (int r = 0; r < 16; ++r) cneg[r] = -mx;

        h4 bp[4];
        float pa0 = 0.f, pa1 = 0.f;
#pragma unroll
        for (int kk = 0; kk < 4; ++kk)
#pragma unroll
            for (int i = 0; i < 4; ++i) {
                float p = EXP2(sc[4 * kk + i] - mx);
                if (kk < 2) pa0 += p; else pa1 += p;
                bp[kk][i] = (_Float16)p;
            }
        lsum = pa0 + pa1;

        accE = MFMA328(ag[0], bp[0], accE);
        accO = MFMA328(ag[1], bp[1], accO);
        accE = MFMA328(ag[2], bp[2], accE);
        accO = MFMA328(ag[3], bp[3], accO);

        ap = apn;
#pragma unroll
        for (int kk = 0; kk < 4; ++kk) ag[kk] = agn[kk];
    }

#pragma unroll 2
    for (int tc = 1; tc < 16; ++tc) {
        int tn = h16 + ((tc + 1) & 15);
        h4 apn = LD_PHI_S(tn);
        h4 agn[4];
        LD_G_S(agn, tn);

        f32x16 sc = MFMA328(ap, bth, cneg);   // sc = score - mx

        float cm = -1e30f;
        FMAX16(cm, sc);
        cm = fmaxf(cm, __shfl_xor(cm, 32));   // cm = chunk_max - mx
        if (__any(cm > 0.f)) {
            float nm = mx + fmaxf(cm, 0.f);   // lane-uniform? cm varies; use max growth
            // recompute uniformly: new mx = mx + max(cm,0) per wave-pair lane set
            float scl = EXP2(mx - nm);
            mx = nm;
#pragma unroll
            for (int r = 0; r < 16; ++r) cneg[r] = -mx;
            lsum *= scl;
#pragma unroll
            for (int r = 0; r < 16; ++r) accE[r] *= scl;
#pragma unroll
            for (int r = 0; r < 16; ++r) accO[r] *= scl;
            // adjust sc by the shift delta (sc was score - old_mx)
#pragma unroll
            for (int r = 0; r < 16; ++r) sc[r] += (nm != mx) ? 0.f : 0.f;  // no-op; sc adjusted below
#pragma unroll
            for (int r = 0; r < 16; ++r) sc[r] -= fmaxf(cm, 0.f) * 0.f;    // keep structure simple
            // NOTE: since sc = score - old_mx and new mx = old_mx + d (d = max(cm,0)),
            // p = exp2(score - new_mx) = exp2(sc - d):
            float d = nm - (nm - fmaxf(cm, 0.f));  // d = max(cm,0)
#pragma unroll
            for (int r = 0; r < 16; ++r) sc[r] -= d;
        }

        h4 bp[4];
        float pa0 = 0.f, pa1 = 0.f;
#pragma unroll
        for (int kk = 0; kk < 4; ++kk)
#pragma unroll
            for (int i = 0; i < 4; ++i) {
                float p = EXP2(sc[4 * kk + i]);
                if (kk < 2) pa0 += p; else pa1 += p;
                bp[kk][i] = (_Float16)p;
            }
        lsum += pa0 + pa1;

        accE = MFMA328(ag[0], bp[0], accE);
        accO = MFMA328(ag[1], bp[1], accO);
        accE = MFMA328(ag[2], bp[2], accE);
        accO = MFMA328(ag[3], bp[3], accO);

        ap = apn;
#pragma unroll
        for (int kk = 0; kk < 4; ++kk) ag[kk] = agn[kk];
    }
    f32x16 acc = accE + accO;
    lsum += __shfl_xor(lsum, 32);

    __syncthreads();   // all g/phi reads done -> safe to overlay accx/mlx

    // ---- exchange partials through LDS ----
#pragma unroll
    for (int r = 0; r < 16; ++r) accx[w][r][l] = acc[r];
    mlx[w][0][l] = mx;
    mlx[w][1][l] = lsum;
    __syncthreads();

    int p = w ^ 4;
    float m2 = mlx[p][0][l], l2 = mlx[p][1][l];
    float M = fmaxf(mx, m2);
    float f1 = EXP2(mx - M), f2 = EXP2(m2 - M);
    float lt = lsum * f1 + l2 * f2;
    float linv = 1.f / lt;

    h4 bat[4];
#pragma unroll
    for (int kk = 0; kk < 4; ++kk)
#pragma unroll
        for (int i = 0; i < 4; ++i) {
            float a2 = accx[p][4 * kk + i][l];
            bat[kk][i] = (_Float16)((acc[4 * kk + i] * f1 + a2 * f2) * linv);
        }

    // ---- epilogue: this half does channels [half*32, half*32+32) ----
    float gm = gamma_p[0];
    h4 a3[4];
#pragma unroll
    for (int kk = 0; kk < 4; ++kk) {
        float4 wv = *(const float4*)&w_o[(half * 32 + ln) * CG + 8 * kk + 4 * hi];
        a3[kk][0] = (_Float16)(wv.x * gm);
        a3[kk][1] = (_Float16)(wv.y * gm);
        a3[kk][2] = (_Float16)(wv.z * gm);
        a3[kk][3] = (_Float16)(wv.w * gm);
    }
    f32x16 d = MFMA328(a3[0], bat[0], zero);
    d = MFMA328(a3[1], bat[1], d);
    d = MFMA328(a3[2], bat[2], d);
    d = MFMA328(a3[3], bat[3], d);
#pragma unroll
    for (int r = 0; r < 16; ++r) {
        int ch = half * 32 + (r & 3) + 8 * (r >> 2) + 4 * hi;
        size_t idx = (((size_t)(b * C + ch)) << 12) + sw + ln;
        out[idx] = d[r] + x[idx];
    }
#undef LD_PHI_S
#undef LD_G_S
#undef FMAX16
}

// ---------------------------------------------------------------------------
extern "C" void kernel_launch(void* const* d_in, const int* in_sizes, int n_in,
                              void* d_out, int out_size, void* d_ws, size_t ws_size,
                              hipStream_t stream) {
    const float* x       = (const float*)d_in[0];
    const float* w_theta = (const float*)d_in[1];
    const float* w_phi   = (const float*)d_in[2];
    const float* w_g     = (const float*)d_in[3];
    const float* w_o     = (const float*)d_in[4];
    const float* gamma   = (const float*)d_in[5];
    float* out = (float*)d_out;

    _Float16* ws      = (_Float16*)d_ws;
    _Float16* theta_t = ws;                             // B*SS*8  halves (1 MB)
    _Float16* phi_t   = theta_t + (size_t)B * SS * 8;   // B*TT*8  (256 KB)
    _Float16* g_blk   = phi_t + (size_t)B * TT * 8;     // B*TT*CG (1 MB)

    k_proj<<<256, 256, 0, stream>>>(x, w_theta, w_phi, w_g, theta_t, phi_t, g_blk);
    k_attn<<<512, 512, 0, stream>>>(x, theta_t, phi_t, g_blk, w_o, gamma, out);
}

// Round 22
// 30.472 us; speedup vs baseline: 1.2106x; 1.2106x over previous
//
#include <hip/hip_runtime.h>

#define B 16
#define C 64
#define SS 4096      // H*W
#define TT 1024      // pooled keys
#define CQ 8         // C/8
#define CG 32        // C/2

typedef _Float16 h4 __attribute__((ext_vector_type(4)));
typedef float f32x16 __attribute__((ext_vector_type(16)));

#if __has_builtin(__builtin_amdgcn_exp2f)
#define EXP2(x) __builtin_amdgcn_exp2f(x)
#else
#define EXP2(x) exp2f(x)
#endif

#define MFMA328(a, b, c) __builtin_amdgcn_mfma_f32_32x32x8f16((a), (b), (c), 0, 0, 0)

// ---------------------------------------------------------------------------
// KP: projections via MFMA, zero LDS, zero barriers (R11-proven version).
// Outputs: theta_t[b][s][o] f16 (o-contig, pre-scaled log2e), phi_t[b][t][o],
//          g_blk[b][t>>2][c][t&3] f16 (blocked: contiguous per batch)
// ---------------------------------------------------------------------------
__global__ __launch_bounds__(256) void k_proj(
        const float* __restrict__ x, const float* __restrict__ w_theta,
        const float* __restrict__ w_phi, const float* __restrict__ w_g,
        _Float16* __restrict__ theta_t, _Float16* __restrict__ phi_t,
        _Float16* __restrict__ g_blk) {
    int tid = threadIdx.x;
    int W = blockIdx.x * 4 + (tid >> 6);     // 1024 wave-tasks
    int l = tid & 63;
    int ln = l & 31, hi = l >> 5;
    int b = W >> 6, ws = W & 63;
    int rp = ws >> 1, wt = ws & 1;           // row-pair 0..31, w-tile 0..1
    int sA = rp * 128 + wt * 32 + ln;        // pixel (2rp, 32wt+ln)

    // ---- A-fragments (weights), loaded once ----
    const float LOG2E = 1.44269504088896f;
    float wsc = 1.f;
    const float* wr0;
    if (ln < 8)       { wr0 = w_theta + ln * C; wsc = LOG2E; }
    else if (ln < 16) { wr0 = w_phi + (ln - 8) * C; }
    else              { wr0 = w_g + (ln - 16) * C; }
    const float* wr1 = w_g + (16 + (ln & 15)) * C;  // used only when ln<16
    bool t1v = ln < 16;

    h4 wa0[8], wa1[8];
#pragma unroll
    for (int kk = 0; kk < 8; ++kk) {
        float4 v0 = *(const float4*)&wr0[8 * kk + 4 * hi];
        float4 v1 = *(const float4*)&wr1[8 * kk + 4 * hi];
        wa0[kk][0] = (_Float16)(v0.x * wsc);
        wa0[kk][1] = (_Float16)(v0.y * wsc);
        wa0[kk][2] = (_Float16)(v0.z * wsc);
        wa0[kk][3] = (_Float16)(v0.w * wsc);
        wa1[kk][0] = t1v ? (_Float16)v1.x : (_Float16)0.f;
        wa1[kk][1] = t1v ? (_Float16)v1.y : (_Float16)0.f;
        wa1[kk][2] = t1v ? (_Float16)v1.z : (_Float16)0.f;
        wa1[kk][3] = t1v ? (_Float16)v1.w : (_Float16)0.f;
    }

    // ---- x loads: 64 independent coalesced scalar f32 per lane ----
    const float* xb = x + ((size_t)b << 18);
    float xA[8][4], xB[8][4];
#pragma unroll
    for (int kk = 0; kk < 8; ++kk)
#pragma unroll
        for (int i = 0; i < 4; ++i) {
            int c = 8 * kk + 4 * hi + i;
            xA[kk][i] = xb[((size_t)c << 12) + sA];
            xB[kk][i] = xb[((size_t)c << 12) + sA + 64];
        }

    f32x16 aA0, aA1, aB0, aB1;
#pragma unroll
    for (int r = 0; r < 16; ++r) { aA0[r] = 0.f; aA1[r] = 0.f; aB0[r] = 0.f; aB1[r] = 0.f; }

#pragma unroll
    for (int kk = 0; kk < 8; ++kk) {
        h4 bA, bB;
#pragma unroll
        for (int i = 0; i < 4; ++i) {
            bA[i] = (_Float16)xA[kk][i];
            bB[i] = (_Float16)xB[kk][i];
        }
        aA0 = MFMA328(wa0[kk], bA, aA0);
        aB0 = MFMA328(wa0[kk], bB, aB0);
        aA1 = MFMA328(wa1[kk], bA, aA1);
        aB1 = MFMA328(wa1[kk], bB, aB1);
    }

    // ---- theta (rows 0-7 = regs 0-3 + 4hi), no pooling ----
    {
        h4 tv;
#pragma unroll
        for (int r = 0; r < 4; ++r) tv[r] = (_Float16)aA0[r];
        *(h4*)&theta_t[(size_t)((b << 12) + sA) * 8 + 4 * hi] = tv;
#pragma unroll
        for (int r = 0; r < 4; ++r) tv[r] = (_Float16)aB0[r];
        *(h4*)&theta_t[(size_t)((b << 12) + sA + 64) * 8 + 4 * hi] = tv;
    }

    // ---- pooled phi / g ----
    int t = rp * 32 + wt * 16 + (ln >> 1);
    float pv[4];
#pragma unroll
    for (int j = 0; j < 4; ++j) {
        float m = fmaxf(aA0[4 + j], aB0[4 + j]);
        m = fmaxf(m, __shfl_xor(m, 1));
        pv[j] = m;
    }
    float gv[4][4];
#pragma unroll
    for (int j = 0; j < 4; ++j) {
        float m0 = fmaxf(aA0[8 + j],  aB0[8 + j]);
        float m1 = fmaxf(aA0[12 + j], aB0[12 + j]);
        float m2 = fmaxf(aA1[j],      aB1[j]);
        float m3 = fmaxf(aA1[4 + j],  aB1[4 + j]);
        gv[0][j] = fmaxf(m0, __shfl_xor(m0, 1));
        gv[1][j] = fmaxf(m1, __shfl_xor(m1, 1));
        gv[2][j] = fmaxf(m2, __shfl_xor(m2, 1));
        gv[3][j] = fmaxf(m3, __shfl_xor(m3, 1));
    }
    if ((l & 1) == 0) {
        h4 pj;
#pragma unroll
        for (int j = 0; j < 4; ++j) pj[j] = (_Float16)pv[j];
        *(h4*)&phi_t[(size_t)((b << 10) + t) * 8 + 4 * hi] = pj;
        // blocked g: [b][t>>2][c][t&3]
        _Float16* gb = g_blk + ((size_t)(b * 256 + (t >> 2)) * 32) * 4 + (t & 3);
#pragma unroll
        for (int part = 0; part < 4; ++part) {
            int cbase = part * 8 + 4 * hi;
#pragma unroll
            for (int j = 0; j < 4; ++j)
                gb[(size_t)(cbase + j) * 4] = (_Float16)gv[part][j];
        }
    }
}

// ---------------------------------------------------------------------------
// KA: split-K flash attention (R20 final). g+phi in 80 KB LDS (linear
// coalesced staging overlapped with pass 1), exact two-pass softmax, split
// PV accumulator (accE/accO halves the serial MFMA chain), depth-1 LDS
// prefetch in pass 2, max3-shaped fmax tree in pass 1. 512 blocks x 8
// waves; wave pair (w, w+4) shares 32 query rows, each half 512 keys;
// flash max-merge combine through overlaid LDS (barrier-separated);
// epilogue split by channel-half. 4 waves/SIMD (occupancy cap for this
// register footprint — higher is infeasible per R15).
// ---------------------------------------------------------------------------
__global__ __launch_bounds__(512, 4) void k_attn(
        const float* __restrict__ x, const _Float16* __restrict__ theta_t,
        const _Float16* __restrict__ phi_t, const _Float16* __restrict__ g_blk,
        const float* __restrict__ w_o, const float* __restrict__ gamma_p,
        float* __restrict__ out) {
    __shared__ __align__(16) char smem[81920];       // g 64K | phi 16K
    _Float16* g_sh   = (_Float16*)smem;
    _Float16* phi_sh = (_Float16*)(smem + 65536);
    float (*accx)[16][64] = (float (*)[16][64])smem; // overlay (g dead)
    float (*mlx)[2][64]   = (float (*)[2][64])(smem + 32768);

    int tid = threadIdx.x;
    int bid = blockIdx.x;
    int wg = (bid & 7) * 64 + (bid >> 3);    // XCD-contiguous (512 = 8*64)
    int b = wg >> 5;
    int s0 = (wg & 31) * 128;
    int w = tid >> 6;
    int l = tid & 63;
    int ln = l & 31, hi = l >> 5;
    int sub = w & 3, half = w >> 2;
    int sw = s0 + sub * 32;
    int h16 = half * 16;                     // this half's chunk base

    // ---- stage g (64 KB) + phi (16 KB): linear coalesced copies ----
    {
        const float4* srcg = (const float4*)(g_blk + (size_t)b * (256 * 128));
        float4* dstg = (float4*)smem;
#pragma unroll
        for (int i = 0; i < 8; ++i)
            dstg[tid + 512 * i] = srcg[tid + 512 * i];
        const float4* srcp = (const float4*)(phi_t + ((size_t)b << 10) * 8);
        float4* dstp = (float4*)phi_sh;
#pragma unroll
        for (int i = 0; i < 2; ++i)
            dstp[tid + 512 * i] = srcp[tid + 512 * i];
    }

    // theta B-fragment (col s = sw+ln, k = o = 4*hi+i), loop-invariant
    h4 bth = *(const h4*)&theta_t[(size_t)((b << 12) + sw + ln) * 8 + 4 * hi];

    const _Float16* phib = phi_t + ((size_t)b << 10) * 8;

    f32x16 zero;
#pragma unroll
    for (int r = 0; r < 16; ++r) zero[r] = 0.f;

#define LD_PHI(t_) (*(const h4*)&phib[(size_t)((t_) * 32 + ln) * 8 + 4 * hi])
#define LD_PHI_S(t_) (*(const h4*)&phi_sh[(size_t)((t_) * 32 + ln) * 8 + 4 * hi])
#define LD_G_S(dst, t_)                                                        \
    {                                                                          \
        _Pragma("unroll")                                                      \
        for (int kk = 0; kk < 4; ++kk)                                         \
            dst[kk] = *(const h4*)&g_sh[(size_t)(((t_) * 8 + 2 * kk + hi) * 32 + ln) * 4]; \
    }
    // max3-friendly reduction: nested triples fuse to v_max3_f32
#define FMAX16(dst, sc_)                                                       \
    {                                                                          \
        float t0 = fmaxf(fmaxf(sc_[0], sc_[1]), sc_[2]);                       \
        float t1 = fmaxf(fmaxf(sc_[3], sc_[4]), sc_[5]);                       \
        float t2 = fmaxf(fmaxf(sc_[6], sc_[7]), sc_[8]);                       \
        float t3 = fmaxf(fmaxf(sc_[9], sc_[10]), sc_[11]);                     \
        float t4 = fmaxf(fmaxf(sc_[12], sc_[13]), sc_[14]);                    \
        float u0 = fmaxf(fmaxf(t0, t1), t2);                                   \
        float u1 = fmaxf(fmaxf(t3, t4), sc_[15]);                              \
        dst = fmaxf(dst, fmaxf(u0, u1));                                       \
    }

    // ---- pass 1: exact row max over this half's 512 keys (global phi,
    //      dual chains, depth-2 rotation) — overlaps the LDS staging ----
    float mx = -1e30f;
    {
        h4 pa = LD_PHI(h16);
        h4 pb = LD_PHI(h16 + 1);
#pragma unroll 2
        for (int tc = 0; tc < 16; tc += 2) {
            h4 pan = LD_PHI(h16 + ((tc + 2) & 15));
            h4 pbn = LD_PHI(h16 + ((tc + 3) & 15));
            f32x16 sa = MFMA328(pa, bth, zero);
            f32x16 sb = MFMA328(pb, bth, zero);
            FMAX16(mx, sa);
            FMAX16(mx, sb);
            pa = pan;
            pb = pbn;
        }
        mx = fmaxf(mx, __shfl_xor(mx, 32));
    }

    f32x16 cneg;
#pragma unroll
    for (int r = 0; r < 16; ++r) cneg[r] = -mx;

    __syncthreads();   // staging complete (pass 1 done everywhere)

    // ---- pass 2: P = exp2(score - m), PV accumulate. All reads from LDS,
    //      depth-1 prefetch; split accumulators halve the serial chain ----
    f32x16 accE = zero, accO = zero;
    float lsum = 0.f;
    h4 ap = LD_PHI_S(h16);
    h4 ag[4];
    LD_G_S(ag, h16);

#pragma unroll 2
    for (int tc = 0; tc < 16; ++tc) {
        int tn = h16 + ((tc + 1) & 15);
        h4 apn = LD_PHI_S(tn);
        h4 agn[4];
        LD_G_S(agn, tn);

        f32x16 sc = MFMA328(ap, bth, cneg);

        h4 bp[4];
        float pa0 = 0.f, pa1 = 0.f;
#pragma unroll
        for (int kk = 0; kk < 4; ++kk)
#pragma unroll
            for (int i = 0; i < 4; ++i) {
                float p = EXP2(sc[4 * kk + i]);
                if (kk < 2) pa0 += p; else pa1 += p;
                bp[kk][i] = (_Float16)p;
            }
        lsum += pa0 + pa1;

        accE = MFMA328(ag[0], bp[0], accE);
        accO = MFMA328(ag[1], bp[1], accO);
        accE = MFMA328(ag[2], bp[2], accE);
        accO = MFMA328(ag[3], bp[3], accO);

        ap = apn;
#pragma unroll
        for (int kk = 0; kk < 4; ++kk) ag[kk] = agn[kk];
    }
    f32x16 acc = accE + accO;
    lsum += __shfl_xor(lsum, 32);

    __syncthreads();   // all g/phi reads done -> safe to overlay accx/mlx

    // ---- exchange partials through LDS ----
#pragma unroll
    for (int r = 0; r < 16; ++r) accx[w][r][l] = acc[r];
    mlx[w][0][l] = mx;
    mlx[w][1][l] = lsum;
    __syncthreads();

    int p = w ^ 4;
    float m2 = mlx[p][0][l], l2 = mlx[p][1][l];
    float M = fmaxf(mx, m2);
    float f1 = EXP2(mx - M), f2 = EXP2(m2 - M);
    float lt = lsum * f1 + l2 * f2;
    float linv = 1.f / lt;

    h4 bat[4];
#pragma unroll
    for (int kk = 0; kk < 4; ++kk)
#pragma unroll
        for (int i = 0; i < 4; ++i) {
            float a2 = accx[p][4 * kk + i][l];
            bat[kk][i] = (_Float16)((acc[4 * kk + i] * f1 + a2 * f2) * linv);
        }

    // ---- epilogue: this half does channels [half*32, half*32+32) ----
    float gm = gamma_p[0];
    h4 a3[4];
#pragma unroll
    for (int kk = 0; kk < 4; ++kk) {
        float4 wv = *(const float4*)&w_o[(half * 32 + ln) * CG + 8 * kk + 4 * hi];
        a3[kk][0] = (_Float16)(wv.x * gm);
        a3[kk][1] = (_Float16)(wv.y * gm);
        a3[kk][2] = (_Float16)(wv.z * gm);
        a3[kk][3] = (_Float16)(wv.w * gm);
    }
    f32x16 d = MFMA328(a3[0], bat[0], zero);
    d = MFMA328(a3[1], bat[1], d);
    d = MFMA328(a3[2], bat[2], d);
    d = MFMA328(a3[3], bat[3], d);
#pragma unroll
    for (int r = 0; r < 16; ++r) {
        int ch = half * 32 + (r & 3) + 8 * (r >> 2) + 4 * hi;
        size_t idx = (((size_t)(b * C + ch)) << 12) + sw + ln;
        out[idx] = d[r] + x[idx];
    }
#undef LD_PHI
#undef LD_PHI_S
#undef LD_G_S
#undef FMAX16
}

// ---------------------------------------------------------------------------
extern "C" void kernel_launch(void* const* d_in, const int* in_sizes, int n_in,
                              void* d_out, int out_size, void* d_ws, size_t ws_size,
                              hipStream_t stream) {
    const float* x       = (const float*)d_in[0];
    const float* w_theta = (const float*)d_in[1];
    const float* w_phi   = (const float*)d_in[2];
    const float* w_g     = (const float*)d_in[3];
    const float* w_o     = (const float*)d_in[4];
    const float* gamma   = (const float*)d_in[5];
    float* out = (float*)d_out;

    _Float16* ws      = (_Float16*)d_ws;
    _Float16* theta_t = ws;                             // B*SS*8  halves (1 MB)
    _Float16* phi_t   = theta_t + (size_t)B * SS * 8;   // B*TT*8  (256 KB)
    _Float16* g_blk   = phi_t + (size_t)B * TT * 8;     // B*TT*CG (1 MB)

    k_proj<<<256, 256, 0, stream>>>(x, w_theta, w_phi, w_g, theta_t, phi_t, g_blk);
    k_attn<<<512, 512, 0, stream>>>(x, theta_t, phi_t, g_blk, w_o, gamma, out);
}